// Round 6
// baseline (351.060 us; speedup 1.0000x reference)
//
#include <hip/hip_runtime.h>
#include <hip/hip_bf16.h>

typedef __attribute__((ext_vector_type(8))) __bf16 bf16x8;
typedef __attribute__((ext_vector_type(4))) float f32x4;

union BF8U { uint4 u; bf16x8 b; };

static __device__ __forceinline__ unsigned short f2bf(float f){
  __bf16 h = (__bf16)f;                       // hw RNE cvt
  return *reinterpret_cast<unsigned short*>(&h);
}

static __device__ __forceinline__ bf16x8 ld_bf8(const unsigned short* p){
  BF8U u; u.u = *reinterpret_cast<const uint4*>(p); return u.b;
}

static __device__ __forceinline__ f32x4 mfma16(bf16x8 a, bf16x8 b, f32x4 c){
  return __builtin_amdgcn_mfma_f32_16x16x32_bf16(a, b, c, 0, 0, 0);
}

// async global->LDS, 16B per lane; LDS dest must be lane-linear (base + lane*16)
static __device__ __forceinline__ void gl_lds16(const unsigned short* g, unsigned short* l){
  __builtin_amdgcn_global_load_lds(
      (const __attribute__((address_space(1))) unsigned int*)g,
      (__attribute__((address_space(3))) unsigned int*)l, 16, 0, 0);
}

// ---------------- prep: 3x LayerNorm (24576 blocks) + 4x weight-T (1024) ----
__global__ __launch_bounds__(256) void prep_kernel(
    const float* __restrict__ Q, const float* __restrict__ K, const float* __restrict__ V,
    const float* __restrict__ gamma, const float* __restrict__ beta,
    unsigned short* __restrict__ lnQ, unsigned short* __restrict__ lnK,
    unsigned short* __restrict__ lnV,
    const float* __restrict__ Wq, const float* __restrict__ Wk,
    const float* __restrict__ Wv, const float* __restrict__ Wo,
    unsigned short* __restrict__ WtQ, unsigned short* __restrict__ WtK,
    unsigned short* __restrict__ WtV, unsigned short* __restrict__ WtO)
{
  __shared__ __align__(16) unsigned short smem[64*72];
  const int bid = (int)blockIdx.x;
  const int t = threadIdx.x;
  if (bid < 24576){
    // ---- LayerNorm ----
    const int sel = bid >> 13;
    const int row = bid & 8191;
    const float* X = sel==0 ? Q : sel==1 ? K : V;
    unsigned short* out = sel==0 ? lnQ : sel==1 ? lnK : lnV;
    float* red = reinterpret_cast<float*>(smem);
    const float4 x = reinterpret_cast<const float4*>(X + (size_t)row*1024)[t];
    float s  = x.x + x.y + x.z + x.w;
    float ss = x.x*x.x + x.y*x.y + x.z*x.z + x.w*x.w;
    for (int off = 1; off < 64; off <<= 1){
      s  += __shfl_xor(s, off);
      ss += __shfl_xor(ss, off);
    }
    const int wv = t >> 6;
    if ((t & 63) == 0){ red[wv] = s; red[4 + wv] = ss; }
    __syncthreads();
    s  = red[0] + red[1] + red[2] + red[3];
    ss = red[4] + red[5] + red[6] + red[7];
    const float mu   = s * (1.0f/1024.0f);
    const float var  = ss * (1.0f/1024.0f) - mu*mu;
    const float rstd = rsqrtf(var + 1e-6f);
    const float4 gm = reinterpret_cast<const float4*>(gamma)[t];
    const float4 bt = reinterpret_cast<const float4*>(beta)[t];
    unsigned short pk[4];
    pk[0] = f2bf((x.x - mu)*rstd*gm.x + bt.x);
    pk[1] = f2bf((x.y - mu)*rstd*gm.y + bt.y);
    pk[2] = f2bf((x.z - mu)*rstd*gm.z + bt.z);
    pk[3] = f2bf((x.w - mu)*rstd*gm.w + bt.w);
    *reinterpret_cast<uint2*>(out + (size_t)row*1024 + t*4) = *reinterpret_cast<uint2*>(pk);
  } else {
    // ---- weight convert+transpose: W (KxN f32) -> Wt (NxK bf16) ----
    const int wid = bid - 24576;
    const int wsel = wid >> 8;
    const float* W = wsel==0 ? Wq : wsel==1 ? Wk : wsel==2 ? Wv : Wo;
    unsigned short* Wt = wsel==0 ? WtQ : wsel==1 ? WtK : wsel==2 ? WtV : WtO;
    unsigned short (*tile)[72] = reinterpret_cast<unsigned short(*)[72]>(smem);
    const int tb = wid & 255;
    const int bk = (tb >> 4) * 64;
    const int bn = (tb & 15) * 64;
    {
      const int kr = t >> 2, nc0 = (t & 3) * 16;
      const float4* src = reinterpret_cast<const float4*>(W + (size_t)(bk + kr)*1024 + bn + nc0);
      for (int q = 0; q < 4; ++q){
        float4 vv = src[q];
        tile[kr][nc0 + q*4 + 0] = f2bf(vv.x);
        tile[kr][nc0 + q*4 + 1] = f2bf(vv.y);
        tile[kr][nc0 + q*4 + 2] = f2bf(vv.z);
        tile[kr][nc0 + q*4 + 3] = f2bf(vv.w);
      }
    }
    __syncthreads();
    {
      const int nr = t >> 2, kc0 = (t & 3) * 16;
      unsigned short outv[16];
      for (int j = 0; j < 16; ++j) outv[j] = tile[kc0 + j][nr];
      uint4* dst = reinterpret_cast<uint4*>(Wt + (size_t)(bn + nr)*1024 + bk + kc0);
      dst[0] = reinterpret_cast<uint4*>(outv)[0];
      dst[1] = reinterpret_cast<uint4*>(outv)[1];
    }
  }
}

// ---------------- QKV projections, one launch (1536 blocks) -----------------
// which = bid/512: 0 -> q (scale log2e, head-major (bh,s,d))
//                  1 -> k (head-major (bh,s,d))
//                  2 -> v (TRANSPOSED head-major (bh,d,s))
// XCD-chunked swizzle: consecutive-mod-8 blocks (same XCD) share 8 bm panels;
// per-XCD working set = 2MB A-panels + 2MB B = 4MB = one L2.
__global__ __launch_bounds__(256) void qkv_kernel(
    const unsigned short* __restrict__ lnQ, const unsigned short* __restrict__ lnK,
    const unsigned short* __restrict__ lnV,
    const unsigned short* __restrict__ WtQ, const unsigned short* __restrict__ WtK,
    const unsigned short* __restrict__ WtV,
    const float* __restrict__ bq, const float* __restrict__ bk,
    const float* __restrict__ bv,
    unsigned short* __restrict__ qb, unsigned short* __restrict__ kb,
    unsigned short* __restrict__ vtb)
{
  __shared__ unsigned short a_lds[128][64];
  __shared__ unsigned short b_lds[128][64];
  const int bid = (int)blockIdx.x;
  const int which = bid >> 9;
  const int inner = bid & 511;
  const int swz = ((inner & 7) << 6) | (inner >> 3);   // XCD-chunked (bijective)
  const unsigned short* A  = which==0 ? lnQ : which==1 ? lnK : lnV;
  const unsigned short* Bt = which==0 ? WtQ : which==1 ? WtK : WtV;
  const float* bias = which==0 ? bq : which==1 ? bk : bv;

  const int t = threadIdx.x;
  const int lane = t & 63;
  const int w = t >> 6;
  const int g = lane >> 4, c = lane & 15;
  const int bm = swz >> 3, bn = swz & 7;
  const int wr = w >> 1, wc = w & 1;
  const int row0 = bm * 128, col0 = bn * 128;

  f32x4 acc[4][4];
  const f32x4 fz = {0.f, 0.f, 0.f, 0.f};
  for (int i = 0; i < 4; ++i) for (int j = 0; j < 4; ++j) acc[i][j] = fz;

  for (int kb_ = 0; kb_ < 1024; kb_ += 64){
    for (int i = 0; i < 4; ++i){
      const int cid = t + i*256;
      const int r = cid >> 3, ch = cid & 7;
      const int chs = (ch ^ (r & 7)) * 8;
      gl_lds16(&A [(size_t)(row0 + r)*1024 + kb_ + chs], &a_lds[0][0] + cid*8);
      gl_lds16(&Bt[(size_t)(col0 + r)*1024 + kb_ + chs], &b_lds[0][0] + cid*8);
    }
    __syncthreads();
    bf16x8 af[4][2], bfr[4][2];
    for (int mt = 0; mt < 4; ++mt)
      for (int kc = 0; kc < 2; ++kc){
        const int R = wr*64 + mt*16 + c;
        af[mt][kc] = ld_bf8(&a_lds[R][((kc*4 + g) ^ (R & 7))*8]);
      }
    for (int nt = 0; nt < 4; ++nt)
      for (int kc = 0; kc < 2; ++kc){
        const int R = wc*64 + nt*16 + c;
        bfr[nt][kc] = ld_bf8(&b_lds[R][((kc*4 + g) ^ (R & 7))*8]);
      }
    for (int kc = 0; kc < 2; ++kc)
      for (int mt = 0; mt < 4; ++mt)
        for (int nt = 0; nt < 4; ++nt)
          acc[mt][nt] = mfma16(af[mt][kc], bfr[nt][kc], acc[mt][nt]);
    __syncthreads();
  }

  const float scale = (which == 0) ? 1.4426950408889634f : 1.0f;  // fold log2e into q
  unsigned short* outb = which==0 ? qb : kb;
  for (int mt = 0; mt < 4; ++mt){
    for (int nt = 0; nt < 4; ++nt){
      const int gcol = col0 + wc*64 + nt*16 + c;
      const float bv_ = bias[gcol];
      const int hh = gcol >> 6, d = gcol & 63;
      if (which == 2){
        const int grow0 = row0 + wr*64 + mt*16 + g*4;
        const int bidx = grow0 >> 11, s0 = grow0 & 2047;
        unsigned short pk[4];
        for (int r = 0; r < 4; ++r) pk[r] = f2bf(acc[mt][nt][r] + bv_);
        *reinterpret_cast<uint2*>(&vtb[((size_t)((bidx*16 + hh)*64 + d))*2048 + s0]) =
          *reinterpret_cast<uint2*>(pk);
      } else {
        for (int r = 0; r < 4; ++r){
          const int grow = row0 + wr*64 + mt*16 + g*4 + r;
          const int bidx = grow >> 11, s = grow & 2047;
          outb[((size_t)(bidx*16 + hh)*2048 + s)*64 + d] = f2bf((acc[mt][nt][r] + bv_)*scale);
        }
      }
    }
  }
}

// ---------------- output projection + residual (f32 out) --------------------
__global__ __launch_bounds__(256) void ogemm_kernel(
    const unsigned short* __restrict__ A,
    const unsigned short* __restrict__ Bt,
    const float* __restrict__ bias,
    const float* __restrict__ residual,
    float* __restrict__ outf)
{
  __shared__ unsigned short a_lds[128][64];
  __shared__ unsigned short b_lds[128][64];
  const int t = threadIdx.x;
  const int inner = (int)blockIdx.x;
  const int swz = ((inner & 7) << 6) | (inner >> 3);   // XCD-chunked
  const int lane = t & 63;
  const int w = t >> 6;
  const int g = lane >> 4, c = lane & 15;
  const int bm = swz >> 3, bn = swz & 7;
  const int wr = w >> 1, wc = w & 1;
  const int row0 = bm * 128, col0 = bn * 128;

  f32x4 acc[4][4];
  const f32x4 fz = {0.f, 0.f, 0.f, 0.f};
  for (int i = 0; i < 4; ++i) for (int j = 0; j < 4; ++j) acc[i][j] = fz;

  for (int kb_ = 0; kb_ < 1024; kb_ += 64){
    for (int i = 0; i < 4; ++i){
      const int cid = t + i*256;
      const int r = cid >> 3, ch = cid & 7;
      const int chs = (ch ^ (r & 7)) * 8;
      gl_lds16(&A [(size_t)(row0 + r)*1024 + kb_ + chs], &a_lds[0][0] + cid*8);
      gl_lds16(&Bt[(size_t)(col0 + r)*1024 + kb_ + chs], &b_lds[0][0] + cid*8);
    }
    __syncthreads();
    bf16x8 af[4][2], bfr[4][2];
    for (int mt = 0; mt < 4; ++mt)
      for (int kc = 0; kc < 2; ++kc){
        const int R = wr*64 + mt*16 + c;
        af[mt][kc] = ld_bf8(&a_lds[R][((kc*4 + g) ^ (R & 7))*8]);
      }
    for (int nt = 0; nt < 4; ++nt)
      for (int kc = 0; kc < 2; ++kc){
        const int R = wc*64 + nt*16 + c;
        bfr[nt][kc] = ld_bf8(&b_lds[R][((kc*4 + g) ^ (R & 7))*8]);
      }
    for (int kc = 0; kc < 2; ++kc)
      for (int mt = 0; mt < 4; ++mt)
        for (int nt = 0; nt < 4; ++nt)
          acc[mt][nt] = mfma16(af[mt][kc], bfr[nt][kc], acc[mt][nt]);
    __syncthreads();
  }

  for (int mt = 0; mt < 4; ++mt){
    for (int nt = 0; nt < 4; ++nt){
      const int gcol = col0 + wc*64 + nt*16 + c;
      const float bv_ = bias[gcol];
      for (int r = 0; r < 4; ++r){
        const int grow = row0 + wr*64 + mt*16 + g*4 + r;
        const size_t idx = (size_t)grow*1024 + gcol;
        outf[idx] = acc[mt][nt][r] + bv_ + residual[idx];
      }
    }
  }
}

// ---------------- Causal flash attention, 4 waves / 256 threads -------------
// q,k: (b*16+h, s, 64) bf16 (q pre-scaled by log2e).  vt: (b*16+h, 64, s).
// o: (b, s, h*64+d) bf16.
// Block = 64-row q-chunk pair {p, 31-p} of one (b,h): exactly 33 kv-tiles.
// grid 1024 (16 pairs x 64 bh), XCD-chunked so each XCD owns 8 bh (4MB K+V
// working set = one L2). Wave w owns 16 q-rows; every staged tile is live for
// all waves (no wave-skip); only the last tile per half needs the mask.
// Swapped QK^T -> S^T (kv=16ni+4g+r, q=c); swapped PV -> O^T (d=16ni+4g+r, q=c).
__global__ __launch_bounds__(256) void attn_kernel(
    const unsigned short* __restrict__ qg,
    const unsigned short* __restrict__ kg,
    const unsigned short* __restrict__ vtg,
    unsigned short* __restrict__ og)
{
  __shared__ unsigned short k_lds[64][64];
  __shared__ unsigned short vt_lds[64][64];
  __shared__ unsigned short p_lds[4][16][72];
  const int t = threadIdx.x;
  const int lane = t & 63;
  const int w = t >> 6;                        // 0..3
  const int g = lane >> 4, c = lane & 15;
  const int orig = (int)blockIdx.x;            // 1024 blocks
  const int swz = ((orig & 7) << 7) | (orig >> 3);  // XCD-chunked (bijective)
  const int bh = swz >> 4;                     // 8 bh per XCD
  const int p  = swz & 15;                     // 16 chunk-pairs
  const size_t base = (size_t)bh * 2048 * 64;
  const int bidx = bh >> 4, hh = bh & 15;
  const float NEG = -__builtin_inff();
  const f32x4 fz = {0.f,0.f,0.f,0.f};

  for (int half = 0; half < 2; ++half){
    const int qb_ = half ? (31 - p) : p;       // 64-row chunk index
    const int qw = qb_*64 + w*16;

    bf16x8 qf[2];
    for (int kc = 0; kc < 2; ++kc)
      qf[kc] = ld_bf8(&qg[base + (size_t)(qw + c)*64 + kc*32 + g*8]);

    f32x4 o_acc[4];
    for (int i = 0; i < 4; ++i) o_acc[i] = fz;
    float m_run = NEG, l_run = 0.f;

    const int nkv = qb_ + 1;
    for (int kvt = 0; kvt < nkv; ++kvt){
      const int kv0 = kvt * 64;
      for (int i = 0; i < 2; ++i){
        const int cid = t + i*256;
        const int r = cid >> 3, ch = cid & 7;
        const int chs = (ch ^ (r & 7)) * 8;
        gl_lds16(&kg [base + (size_t)(kv0 + r)*64 + chs], &k_lds[0][0]  + cid*8);
        gl_lds16(&vtg[base + (size_t)r*2048 + kv0 + chs], &vt_lds[0][0] + cid*8);
      }
      __syncthreads();

      // S^T = K @ Q^T   (scores already in log2 domain via q pre-scale)
      bf16x8 kf[4][2];
      for (int ni = 0; ni < 4; ++ni)
        for (int kc = 0; kc < 2; ++kc){
          const int R = ni*16 + c;
          kf[ni][kc] = ld_bf8(&k_lds[R][((kc*4 + g) ^ (R & 7))*8]);
        }
      f32x4 st[4];
      for (int i = 0; i < 4; ++i) st[i] = fz;
      __builtin_amdgcn_s_setprio(1);
      for (int kc = 0; kc < 2; ++kc)
        for (int ni = 0; ni < 4; ++ni)
          st[ni] = mfma16(kf[ni][kc], qf[kc], st[ni]);
      __builtin_amdgcn_s_setprio(0);

      const int qglob = qw + c;
      float tmax = NEG;
      if (kvt == qb_){               // diagonal tile: apply causal mask
        for (int ni = 0; ni < 4; ++ni)
          for (int r = 0; r < 4; ++r){
            const int kvglob = kv0 + ni*16 + g*4 + r;
            float sv = (kvglob <= qglob) ? st[ni][r] : NEG;
            st[ni][r] = sv;
            tmax = fmaxf(tmax, sv);
          }
      } else {
        for (int ni = 0; ni < 4; ++ni)
          for (int r = 0; r < 4; ++r)
            tmax = fmaxf(tmax, st[ni][r]);
      }
      tmax = fmaxf(tmax, __shfl_xor(tmax, 16));
      tmax = fmaxf(tmax, __shfl_xor(tmax, 32));

      // defer-max (T13): skip rescale when growth <= 11.5 log2-units (e^8)
      const bool defer = __all(tmax - m_run <= 11.5f);
      if (!defer){
        const float m_new = fmaxf(m_run, tmax);
        const float alpha = __builtin_amdgcn_exp2f(m_run - m_new);
        m_run = m_new;
        l_run *= alpha;
        for (int ni = 0; ni < 4; ++ni){
          o_acc[ni][0] *= alpha; o_acc[ni][1] *= alpha;
          o_acc[ni][2] *= alpha; o_acc[ni][3] *= alpha;
        }
      }
      float tsum = 0.f;
      for (int ni = 0; ni < 4; ++ni){
        unsigned short pk[4];
        for (int r = 0; r < 4; ++r){
          const float pe = __builtin_amdgcn_exp2f(st[ni][r] - m_run);
          tsum += pe;
          pk[r] = f2bf(pe);
        }
        *reinterpret_cast<uint2*>(&p_lds[w][c][ni*16 + g*4]) =
          *reinterpret_cast<uint2*>(pk);
      }
      tsum += __shfl_xor(tsum, 16);
      tsum += __shfl_xor(tsum, 32);
      l_run += tsum;

      // O^T += V^T @ P^T
      bf16x8 vf[4][2], pf[2];
      for (int ni = 0; ni < 4; ++ni)
        for (int kc = 0; kc < 2; ++kc){
          const int R = ni*16 + c;
          vf[ni][kc] = ld_bf8(&vt_lds[R][((kc*4 + g) ^ (R & 7))*8]);
        }
      for (int kc = 0; kc < 2; ++kc)
        pf[kc] = ld_bf8(&p_lds[w][c][kc*32 + g*8]);
      __builtin_amdgcn_s_setprio(1);
      for (int kc = 0; kc < 2; ++kc)
        for (int ni = 0; ni < 4; ++ni)
          o_acc[ni] = mfma16(vf[ni][kc], pf[kc], o_acc[ni]);
      __builtin_amdgcn_s_setprio(0);

      __syncthreads();
    }

    const float invl = 1.0f / l_run;
    const int s = qw + c;
    const size_t obase = ((size_t)(bidx*2048 + s))*1024 + hh*64;
    for (int ni = 0; ni < 4; ++ni){
      unsigned short pk[4];
      pk[0] = f2bf(o_acc[ni][0]*invl);
      pk[1] = f2bf(o_acc[ni][1]*invl);
      pk[2] = f2bf(o_acc[ni][2]*invl);
      pk[3] = f2bf(o_acc[ni][3]*invl);
      *reinterpret_cast<uint2*>(&og[obase + ni*16 + g*4]) =
        *reinterpret_cast<uint2*>(pk);
    }
  }
}

// ---------------------------------------------------------------------------
extern "C" void kernel_launch(void* const* d_in, const int* in_sizes, int n_in,
                              void* d_out, int out_size, void* d_ws, size_t ws_size,
                              hipStream_t stream)
{
  (void)in_sizes; (void)n_in; (void)out_size;
  const float* Q  = (const float*)d_in[0];
  const float* K  = (const float*)d_in[1];
  const float* V  = (const float*)d_in[2];
  const float* Wq = (const float*)d_in[3];
  const float* bq = (const float*)d_in[4];
  const float* Wk = (const float*)d_in[5];
  const float* bk = (const float*)d_in[6];
  const float* Wv = (const float*)d_in[7];
  const float* bv = (const float*)d_in[8];
  const float* Wo = (const float*)d_in[9];
  const float* bo = (const float*)d_in[10];
  const float* gamma = (const float*)d_in[11];
  const float* beta  = (const float*)d_in[12];

  const size_t MB = 1024ull*1024ull;
  if (ws_size < 104*MB) return;
  char* ws = (char*)d_ws;
  unsigned short* lnQ = (unsigned short*)(ws + 0*MB);
  unsigned short* lnK = (unsigned short*)(ws + 16*MB);
  unsigned short* lnV = (unsigned short*)(ws + 32*MB);
  unsigned short* attn_out = lnQ;  // lnQ dead after qkv projections
  unsigned short* WtQ = (unsigned short*)(ws + 48*MB);
  unsigned short* WtK = (unsigned short*)(ws + 50*MB);
  unsigned short* WtV = (unsigned short*)(ws + 52*MB);
  unsigned short* WtO = (unsigned short*)(ws + 54*MB);
  unsigned short* qb  = (unsigned short*)(ws + 56*MB);
  unsigned short* kb  = (unsigned short*)(ws + 72*MB);
  unsigned short* vtb = (unsigned short*)(ws + 88*MB);  // V^T head-major
  float* out = (float*)d_out;

  prep_kernel<<<25600, 256, 0, stream>>>(Q, K, V, gamma, beta, lnQ, lnK, lnV,
                                         Wq, Wk, Wv, Wo, WtQ, WtK, WtV, WtO);
  qkv_kernel<<<1536, 256, 0, stream>>>(lnQ, lnK, lnV, WtQ, WtK, WtV,
                                       bq, bk, bv, qb, kb, vtb);
  attn_kernel<<<1024, 256, 0, stream>>>(qb, kb, vtb, attn_out);
  ogemm_kernel<<<512, 256, 0, stream>>>(attn_out, WtO, bo, Q, out);
}

// Round 7
// 314.384 us; speedup vs baseline: 1.1167x; 1.1167x over previous
//
#include <hip/hip_runtime.h>
#include <hip/hip_bf16.h>

typedef __attribute__((ext_vector_type(8))) __bf16 bf16x8;
typedef __attribute__((ext_vector_type(4))) float f32x4;

union BF8U { uint4 u; bf16x8 b; };

static __device__ __forceinline__ unsigned short f2bf(float f){
  __bf16 h = (__bf16)f;                       // hw RNE cvt
  return *reinterpret_cast<unsigned short*>(&h);
}

static __device__ __forceinline__ bf16x8 ld_bf8(const unsigned short* p){
  BF8U u; u.u = *reinterpret_cast<const uint4*>(p); return u.b;
}

static __device__ __forceinline__ f32x4 mfma16(bf16x8 a, bf16x8 b, f32x4 c){
  return __builtin_amdgcn_mfma_f32_16x16x32_bf16(a, b, c, 0, 0, 0);
}

// async global->LDS, 16B per lane; LDS dest must be lane-linear (base + lane*16)
static __device__ __forceinline__ void gl_lds16(const unsigned short* g, unsigned short* l){
  __builtin_amdgcn_global_load_lds(
      (const __attribute__((address_space(1))) unsigned int*)g,
      (__attribute__((address_space(3))) unsigned int*)l, 16, 0, 0);
}

// ---------------- prep: LN wave-per-row (6144 blocks) + 4x weight-T (1024) --
// LN: one wave owns one row of 1024. 16 f32/lane, shfl-only reduce, no LDS,
// no barriers, 512B-contiguous loads/stores.
__global__ __launch_bounds__(256) void prep_kernel(
    const float* __restrict__ Q, const float* __restrict__ K, const float* __restrict__ V,
    const float* __restrict__ gamma, const float* __restrict__ beta,
    unsigned short* __restrict__ lnQ, unsigned short* __restrict__ lnK,
    unsigned short* __restrict__ lnV,
    const float* __restrict__ Wq, const float* __restrict__ Wk,
    const float* __restrict__ Wv, const float* __restrict__ Wo,
    unsigned short* __restrict__ WtQ, unsigned short* __restrict__ WtK,
    unsigned short* __restrict__ WtV, unsigned short* __restrict__ WtO)
{
  const int bid = (int)blockIdx.x;
  const int t = threadIdx.x;
  if (bid < 6144){
    // ---- LayerNorm: row = global wave id ----
    const int row = bid*4 + (t >> 6);          // 0..24575
    const int lane = t & 63;
    const int sel = row >> 13;                 // 0:Q 1:K 2:V
    const int r0 = row & 8191;
    const float* X = sel==0 ? Q : sel==1 ? K : V;
    unsigned short* out = sel==0 ? lnQ : sel==1 ? lnK : lnV;
    const float4* xp = reinterpret_cast<const float4*>(X + (size_t)r0*1024);
    float4 xv[4];
    float s = 0.f, ss = 0.f;
    for (int i = 0; i < 4; ++i){
      xv[i] = xp[lane + i*64];
      s  += xv[i].x + xv[i].y + xv[i].z + xv[i].w;
      ss += xv[i].x*xv[i].x + xv[i].y*xv[i].y + xv[i].z*xv[i].z + xv[i].w*xv[i].w;
    }
    for (int off = 1; off < 64; off <<= 1){
      s  += __shfl_xor(s, off);
      ss += __shfl_xor(ss, off);
    }
    const float mu   = s * (1.0f/1024.0f);
    const float var  = ss * (1.0f/1024.0f) - mu*mu;
    const float rstd = rsqrtf(var + 1e-6f);
    for (int i = 0; i < 4; ++i){
      const float4 gm = reinterpret_cast<const float4*>(gamma)[lane + i*64];
      const float4 bt = reinterpret_cast<const float4*>(beta )[lane + i*64];
      unsigned short pk[4];
      pk[0] = f2bf((xv[i].x - mu)*rstd*gm.x + bt.x);
      pk[1] = f2bf((xv[i].y - mu)*rstd*gm.y + bt.y);
      pk[2] = f2bf((xv[i].z - mu)*rstd*gm.z + bt.z);
      pk[3] = f2bf((xv[i].w - mu)*rstd*gm.w + bt.w);
      *reinterpret_cast<uint2*>(out + (size_t)r0*1024 + (lane + i*64)*4) =
        *reinterpret_cast<uint2*>(pk);
    }
  } else {
    // ---- weight convert+transpose: W (KxN f32) -> Wt (NxK bf16) ----
    __shared__ unsigned short tile[64][72];
    const int wid = bid - 6144;
    const int wsel = wid >> 8;
    const float* W = wsel==0 ? Wq : wsel==1 ? Wk : wsel==2 ? Wv : Wo;
    unsigned short* Wt = wsel==0 ? WtQ : wsel==1 ? WtK : wsel==2 ? WtV : WtO;
    const int tb = wid & 255;
    const int bk = (tb >> 4) * 64;
    const int bn = (tb & 15) * 64;
    {
      const int kr = t >> 2, nc0 = (t & 3) * 16;
      const float4* src = reinterpret_cast<const float4*>(W + (size_t)(bk + kr)*1024 + bn + nc0);
      for (int q = 0; q < 4; ++q){
        float4 vv = src[q];
        tile[kr][nc0 + q*4 + 0] = f2bf(vv.x);
        tile[kr][nc0 + q*4 + 1] = f2bf(vv.y);
        tile[kr][nc0 + q*4 + 2] = f2bf(vv.z);
        tile[kr][nc0 + q*4 + 3] = f2bf(vv.w);
      }
    }
    __syncthreads();
    {
      const int nr = t >> 2, kc0 = (t & 3) * 16;
      unsigned short outv[16];
      for (int j = 0; j < 16; ++j) outv[j] = tile[kc0 + j][nr];
      uint4* dst = reinterpret_cast<uint4*>(Wt + (size_t)(bn + nr)*1024 + bk + kc0);
      dst[0] = reinterpret_cast<uint4*>(outv)[0];
      dst[1] = reinterpret_cast<uint4*>(outv)[1];
    }
  }
}

// ---------------- QKV projections, one launch (1536 blocks) -----------------
// which = bid/512: 0 -> q (scale log2e, head-major (bh,s,d))
//                  1 -> k (head-major (bh,s,d))
//                  2 -> v (TRANSPOSED head-major (bh,d,s))
// XCD-chunked swizzle: consecutive-mod-8 blocks (same XCD) share 8 bm panels;
// per-XCD working set = 2MB A-panels + 2MB B = 4MB = one L2.
__global__ __launch_bounds__(256) void qkv_kernel(
    const unsigned short* __restrict__ lnQ, const unsigned short* __restrict__ lnK,
    const unsigned short* __restrict__ lnV,
    const unsigned short* __restrict__ WtQ, const unsigned short* __restrict__ WtK,
    const unsigned short* __restrict__ WtV,
    const float* __restrict__ bq, const float* __restrict__ bk,
    const float* __restrict__ bv,
    unsigned short* __restrict__ qb, unsigned short* __restrict__ kb,
    unsigned short* __restrict__ vtb)
{
  __shared__ unsigned short a_lds[128][64];
  __shared__ unsigned short b_lds[128][64];
  const int bid = (int)blockIdx.x;
  const int which = bid >> 9;
  const int inner = bid & 511;
  const int swz = ((inner & 7) << 6) | (inner >> 3);   // XCD-chunked (bijective)
  const unsigned short* A  = which==0 ? lnQ : which==1 ? lnK : lnV;
  const unsigned short* Bt = which==0 ? WtQ : which==1 ? WtK : WtV;
  const float* bias = which==0 ? bq : which==1 ? bk : bv;

  const int t = threadIdx.x;
  const int lane = t & 63;
  const int w = t >> 6;
  const int g = lane >> 4, c = lane & 15;
  const int bm = swz >> 3, bn = swz & 7;
  const int wr = w >> 1, wc = w & 1;
  const int row0 = bm * 128, col0 = bn * 128;

  f32x4 acc[4][4];
  const f32x4 fz = {0.f, 0.f, 0.f, 0.f};
  for (int i = 0; i < 4; ++i) for (int j = 0; j < 4; ++j) acc[i][j] = fz;

  for (int kb_ = 0; kb_ < 1024; kb_ += 64){
    for (int i = 0; i < 4; ++i){
      const int cid = t + i*256;
      const int r = cid >> 3, ch = cid & 7;
      const int chs = (ch ^ (r & 7)) * 8;
      gl_lds16(&A [(size_t)(row0 + r)*1024 + kb_ + chs], &a_lds[0][0] + cid*8);
      gl_lds16(&Bt[(size_t)(col0 + r)*1024 + kb_ + chs], &b_lds[0][0] + cid*8);
    }
    __syncthreads();
    bf16x8 af[4][2], bfr[4][2];
    for (int mt = 0; mt < 4; ++mt)
      for (int kc = 0; kc < 2; ++kc){
        const int R = wr*64 + mt*16 + c;
        af[mt][kc] = ld_bf8(&a_lds[R][((kc*4 + g) ^ (R & 7))*8]);
      }
    for (int nt = 0; nt < 4; ++nt)
      for (int kc = 0; kc < 2; ++kc){
        const int R = wc*64 + nt*16 + c;
        bfr[nt][kc] = ld_bf8(&b_lds[R][((kc*4 + g) ^ (R & 7))*8]);
      }
    for (int kc = 0; kc < 2; ++kc)
      for (int mt = 0; mt < 4; ++mt)
        for (int nt = 0; nt < 4; ++nt)
          acc[mt][nt] = mfma16(af[mt][kc], bfr[nt][kc], acc[mt][nt]);
    __syncthreads();
  }

  const float scale = (which == 0) ? 1.4426950408889634f : 1.0f;  // fold log2e into q
  unsigned short* outb = which==0 ? qb : kb;
  for (int mt = 0; mt < 4; ++mt){
    for (int nt = 0; nt < 4; ++nt){
      const int gcol = col0 + wc*64 + nt*16 + c;
      const float bv_ = bias[gcol];
      const int hh = gcol >> 6, d = gcol & 63;
      if (which == 2){
        const int grow0 = row0 + wr*64 + mt*16 + g*4;
        const int bidx = grow0 >> 11, s0 = grow0 & 2047;
        unsigned short pk[4];
        for (int r = 0; r < 4; ++r) pk[r] = f2bf(acc[mt][nt][r] + bv_);
        *reinterpret_cast<uint2*>(&vtb[((size_t)((bidx*16 + hh)*64 + d))*2048 + s0]) =
          *reinterpret_cast<uint2*>(pk);
      } else {
        for (int r = 0; r < 4; ++r){
          const int grow = row0 + wr*64 + mt*16 + g*4 + r;
          const int bidx = grow >> 11, s = grow & 2047;
          outb[((size_t)(bidx*16 + hh)*2048 + s)*64 + d] = f2bf((acc[mt][nt][r] + bv_)*scale);
        }
      }
    }
  }
}

// ---------------- output projection + residual (f32 out) --------------------
__global__ __launch_bounds__(256) void ogemm_kernel(
    const unsigned short* __restrict__ A,
    const unsigned short* __restrict__ Bt,
    const float* __restrict__ bias,
    const float* __restrict__ residual,
    float* __restrict__ outf)
{
  __shared__ unsigned short a_lds[128][64];
  __shared__ unsigned short b_lds[128][64];
  const int t = threadIdx.x;
  const int inner = (int)blockIdx.x;
  const int swz = ((inner & 7) << 6) | (inner >> 3);   // XCD-chunked
  const int lane = t & 63;
  const int w = t >> 6;
  const int g = lane >> 4, c = lane & 15;
  const int bm = swz >> 3, bn = swz & 7;
  const int wr = w >> 1, wc = w & 1;
  const int row0 = bm * 128, col0 = bn * 128;

  f32x4 acc[4][4];
  const f32x4 fz = {0.f, 0.f, 0.f, 0.f};
  for (int i = 0; i < 4; ++i) for (int j = 0; j < 4; ++j) acc[i][j] = fz;

  for (int kb_ = 0; kb_ < 1024; kb_ += 64){
    for (int i = 0; i < 4; ++i){
      const int cid = t + i*256;
      const int r = cid >> 3, ch = cid & 7;
      const int chs = (ch ^ (r & 7)) * 8;
      gl_lds16(&A [(size_t)(row0 + r)*1024 + kb_ + chs], &a_lds[0][0] + cid*8);
      gl_lds16(&Bt[(size_t)(col0 + r)*1024 + kb_ + chs], &b_lds[0][0] + cid*8);
    }
    __syncthreads();
    bf16x8 af[4][2], bfr[4][2];
    for (int mt = 0; mt < 4; ++mt)
      for (int kc = 0; kc < 2; ++kc){
        const int R = wr*64 + mt*16 + c;
        af[mt][kc] = ld_bf8(&a_lds[R][((kc*4 + g) ^ (R & 7))*8]);
      }
    for (int nt = 0; nt < 4; ++nt)
      for (int kc = 0; kc < 2; ++kc){
        const int R = wc*64 + nt*16 + c;
        bfr[nt][kc] = ld_bf8(&b_lds[R][((kc*4 + g) ^ (R & 7))*8]);
      }
    for (int kc = 0; kc < 2; ++kc)
      for (int mt = 0; mt < 4; ++mt)
        for (int nt = 0; nt < 4; ++nt)
          acc[mt][nt] = mfma16(af[mt][kc], bfr[nt][kc], acc[mt][nt]);
    __syncthreads();
  }

  for (int mt = 0; mt < 4; ++mt){
    for (int nt = 0; nt < 4; ++nt){
      const int gcol = col0 + wc*64 + nt*16 + c;
      const float bv_ = bias[gcol];
      for (int r = 0; r < 4; ++r){
        const int grow = row0 + wr*64 + mt*16 + g*4 + r;
        const size_t idx = (size_t)grow*1024 + gcol;
        outf[idx] = acc[mt][nt][r] + bv_ + residual[idx];
      }
    }
  }
}

// ---------------- Causal flash attention, 8 waves / 512 threads -------------
// q,k: (b*16+h, s, 64) bf16 (q pre-scaled by log2e).  vt: (b*16+h, 64, s).
// o: (b, s, h*64+d) bf16.  Block = q-block pair {p, 15-p} of one (b,h):
// exactly 34 kv-tiles. Wave w owns 16 q-rows. Swapped QK^T -> S^T
// (kv=16ni+4g+r, q=c); swapped PV -> O^T (d=16ni+4g+r, q=c).
// Row-sum l computed via MFMA on an all-ones A-fragment: every lane's reg0
// gets sum_kv P[kv][q=c] -> no VALU adds, no shuffles for l.
// blockIdx mapping: same-bh blocks land on one XCD (bh%8) -> K/V L2-local.
__global__ __launch_bounds__(512, 4) void attn_kernel(
    const unsigned short* __restrict__ qg,
    const unsigned short* __restrict__ kg,
    const unsigned short* __restrict__ vtg,
    unsigned short* __restrict__ og)
{
  __shared__ unsigned short k_lds[64][64];
  __shared__ unsigned short vt_lds[64][64];
  __shared__ unsigned short p_lds[8][16][72];
  const int t = threadIdx.x;
  const int lane = t & 63;
  const int w = t >> 6;                        // 0..7
  const int g = lane >> 4, c = lane & 15;
  const int bh = (int)blockIdx.x & 63;
  const int p  = (int)blockIdx.x >> 6;         // 8 pairs
  const size_t base = (size_t)bh * 2048 * 64;
  const int bidx = bh >> 4, hh = bh & 15;
  const float NEG = -__builtin_inff();
  const f32x4 fz = {0.f,0.f,0.f,0.f};
  BF8U onesu; onesu.u = make_uint4(0x3F803F80u,0x3F803F80u,0x3F803F80u,0x3F803F80u);
  const bf16x8 ones = onesu.b;

  // staging coords (512 threads: one gl_lds each for K and Vt)
  const int sr = t >> 3, sch = t & 7;
  const int schs = (sch ^ (sr & 7)) * 8;

  for (int half = 0; half < 2; ++half){
    const int qb_ = half ? (15 - p) : p;
    const int qw = qb_*128 + w*16;

    bf16x8 qf[2];
    for (int kc = 0; kc < 2; ++kc)
      qf[kc] = ld_bf8(&qg[base + (size_t)(qw + c)*64 + kc*32 + g*8]);

    f32x4 o_acc[4];
    for (int i = 0; i < 4; ++i) o_acc[i] = fz;
    f32x4 l_acc = fz;
    float m_run = NEG;

    const int nkv = qb_*2 + 2;
    for (int kvt = 0; kvt < nkv; ++kvt){
      const int kv0 = kvt * 64;
      gl_lds16(&kg [base + (size_t)(kv0 + sr)*64 + schs], &k_lds[0][0]  + t*8);
      gl_lds16(&vtg[base + (size_t)sr*2048 + kv0 + schs], &vt_lds[0][0] + t*8);
      __syncthreads();

      if (kv0 <= qw + 15){
        // S^T = K @ Q^T   (scores already in log2 domain via q pre-scale)
        bf16x8 kf[4][2];
        for (int ni = 0; ni < 4; ++ni)
          for (int kc = 0; kc < 2; ++kc){
            const int R = ni*16 + c;
            kf[ni][kc] = ld_bf8(&k_lds[R][((kc*4 + g) ^ (R & 7))*8]);
          }
        f32x4 st[4];
        for (int i = 0; i < 4; ++i) st[i] = fz;
        __builtin_amdgcn_s_setprio(1);
        for (int kc = 0; kc < 2; ++kc)
          for (int ni = 0; ni < 4; ++ni)
            st[ni] = mfma16(kf[ni][kc], qf[kc], st[ni]);
        __builtin_amdgcn_s_setprio(0);

        const int qglob = qw + c;
        float tmax = NEG;
        if (kv0 + 63 > qw){            // diagonal tile: apply causal mask
          for (int ni = 0; ni < 4; ++ni)
            for (int r = 0; r < 4; ++r){
              const int kvglob = kv0 + ni*16 + g*4 + r;
              float sv = (kvglob <= qglob) ? st[ni][r] : NEG;
              st[ni][r] = sv;
              tmax = fmaxf(tmax, sv);
            }
        } else {
          for (int ni = 0; ni < 4; ++ni)
            for (int r = 0; r < 4; ++r)
              tmax = fmaxf(tmax, st[ni][r]);
        }
        tmax = fmaxf(tmax, __shfl_xor(tmax, 16));
        tmax = fmaxf(tmax, __shfl_xor(tmax, 32));

        // defer-max (T13): skip rescale when growth <= 11.5 log2-units (e^8)
        const bool defer = __all(tmax - m_run <= 11.5f);
        if (!defer){
          const float m_new = fmaxf(m_run, tmax);
          const float alpha = __builtin_amdgcn_exp2f(m_run - m_new);
          m_run = m_new;
          l_acc[0] *= alpha;
          for (int ni = 0; ni < 4; ++ni){
            o_acc[ni][0] *= alpha; o_acc[ni][1] *= alpha;
            o_acc[ni][2] *= alpha; o_acc[ni][3] *= alpha;
          }
        }
        for (int ni = 0; ni < 4; ++ni){
          unsigned short pk[4];
          for (int r = 0; r < 4; ++r)
            pk[r] = f2bf(__builtin_amdgcn_exp2f(st[ni][r] - m_run));
          *reinterpret_cast<uint2*>(&p_lds[w][c][ni*16 + g*4]) =
            *reinterpret_cast<uint2*>(pk);
        }

        // O^T += V^T @ P^T ; l += ones @ P^T (row-sum via matrix pipe)
        bf16x8 vf[4][2], pf[2];
        for (int ni = 0; ni < 4; ++ni)
          for (int kc = 0; kc < 2; ++kc){
            const int R = ni*16 + c;
            vf[ni][kc] = ld_bf8(&vt_lds[R][((kc*4 + g) ^ (R & 7))*8]);
          }
        for (int kc = 0; kc < 2; ++kc)
          pf[kc] = ld_bf8(&p_lds[w][c][kc*32 + g*8]);
        __builtin_amdgcn_s_setprio(1);
        l_acc = mfma16(ones, pf[0], l_acc);
        l_acc = mfma16(ones, pf[1], l_acc);
        for (int kc = 0; kc < 2; ++kc)
          for (int ni = 0; ni < 4; ++ni)
            o_acc[ni] = mfma16(vf[ni][kc], pf[kc], o_acc[ni]);
        __builtin_amdgcn_s_setprio(0);
      }
      __syncthreads();
    }

    const float invl = 1.0f / l_acc[0];
    const int s = qw + c;
    const size_t obase = ((size_t)(bidx*2048 + s))*1024 + hh*64;
    for (int ni = 0; ni < 4; ++ni){
      unsigned short pk[4];
      pk[0] = f2bf(o_acc[ni][0]*invl);
      pk[1] = f2bf(o_acc[ni][1]*invl);
      pk[2] = f2bf(o_acc[ni][2]*invl);
      pk[3] = f2bf(o_acc[ni][3]*invl);
      *reinterpret_cast<uint2*>(&og[obase + ni*16 + g*4]) =
        *reinterpret_cast<uint2*>(pk);
    }
  }
}

// ---------------------------------------------------------------------------
extern "C" void kernel_launch(void* const* d_in, const int* in_sizes, int n_in,
                              void* d_out, int out_size, void* d_ws, size_t ws_size,
                              hipStream_t stream)
{
  (void)in_sizes; (void)n_in; (void)out_size;
  const float* Q  = (const float*)d_in[0];
  const float* K  = (const float*)d_in[1];
  const float* V  = (const float*)d_in[2];
  const float* Wq = (const float*)d_in[3];
  const float* bq = (const float*)d_in[4];
  const float* Wk = (const float*)d_in[5];
  const float* bk = (const float*)d_in[6];
  const float* Wv = (const float*)d_in[7];
  const float* bv = (const float*)d_in[8];
  const float* Wo = (const float*)d_in[9];
  const float* bo = (const float*)d_in[10];
  const float* gamma = (const float*)d_in[11];
  const float* beta  = (const float*)d_in[12];

  const size_t MB = 1024ull*1024ull;
  if (ws_size < 104*MB) return;
  char* ws = (char*)d_ws;
  unsigned short* lnQ = (unsigned short*)(ws + 0*MB);
  unsigned short* lnK = (unsigned short*)(ws + 16*MB);
  unsigned short* lnV = (unsigned short*)(ws + 32*MB);
  unsigned short* attn_out = lnQ;  // lnQ dead after qkv projections
  unsigned short* WtQ = (unsigned short*)(ws + 48*MB);
  unsigned short* WtK = (unsigned short*)(ws + 50*MB);
  unsigned short* WtV = (unsigned short*)(ws + 52*MB);
  unsigned short* WtO = (unsigned short*)(ws + 54*MB);
  unsigned short* qb  = (unsigned short*)(ws + 56*MB);
  unsigned short* kb  = (unsigned short*)(ws + 72*MB);
  unsigned short* vtb = (unsigned short*)(ws + 88*MB);  // V^T head-major
  float* out = (float*)d_out;

  prep_kernel<<<7168, 256, 0, stream>>>(Q, K, V, gamma, beta, lnQ, lnK, lnV,
                                        Wq, Wk, Wv, Wo, WtQ, WtK, WtV, WtO);
  qkv_kernel<<<1536, 256, 0, stream>>>(lnQ, lnK, lnV, WtQ, WtK, WtV,
                                       bq, bk, bv, qb, kb, vtb);
  attn_kernel<<<512, 512, 0, stream>>>(qb, kb, vtb, attn_out);
  ogemm_kernel<<<512, 256, 0, stream>>>(attn_out, WtO, bo, Q, out);
}